// Round 1
// baseline (8998.514 us; speedup 1.0000x reference)
//
#include <hip/hip_runtime.h>

#define SP 4
#define NHEADS 8
#define HD 8

// One block per (window, half, batch). SHIFT is the roll amount on (C,H).
// ACCUM=false: out = val; ACCUM=true: out += val.
template<int SHIFT, bool ACCUM>
__global__ __launch_bounds__(256) void swin_fused(
    const float* __restrict__ x,          // (8,128,192,192)
    const float* __restrict__ qkv_w,      // (192,64) rows: [0:64)=q, [64:128)=k, [128:192)=v
    const float* __restrict__ lepe_w,     // (64,1,3,3)
    const float* __restrict__ bias_table, // (49,8)
    float* __restrict__ out)              // (8,128,192,192)
{
    const int C = 128, HH = 192, WW = 192;
    const int win  = blockIdx.x;          // 0..2303
    const int wy   = win / 48, wx = win % 48;
    const int half = blockIdx.y;
    const int b    = blockIdx.z;
    const int tid  = threadIdx.x;

    __shared__ float xp[36 * 64];   // 6x6 patch (rolled coords), channel-major inner
    __shared__ float vv[36 * 64];   // v at all 36 patch positions
    __shared__ float qq[16 * 64];   // q at 16 inner tokens
    __shared__ float kk[16 * 64];   // k at 16 inner tokens

    const int ys0 = wy * SP, xs0 = wx * SP;   // window origin in rolled coords

    // ---- stage x patch (apply roll on C and H; zero-pad outside rolled image) ----
    for (int i = tid; i < 36 * 64; i += 256) {
        int p = i >> 6, ch = i & 63;
        int ry = ys0 - 1 + p / 6;
        int rx = xs0 - 1 + p % 6;
        float val = 0.f;
        if (ry >= 0 && ry < HH && rx >= 0 && rx < WW) {
            int oy = ry + SHIFT; if (oy >= HH) oy -= HH;
            int oc = half * 64 + ch + SHIFT; if (oc >= C) oc -= C;
            val = x[((b * C + oc) * HH + oy) * WW + rx];
        }
        xp[i] = val;
    }
    __syncthreads();

    // ---- projections: v for 36 positions, q/k for 16 inner tokens ----
    // 36*64 + 16*64 + 16*64 = 4352 dot products of length 64
    for (int i = tid; i < 4352; i += 256) {
        int row, p, ch;
        float* dst;
        if (i < 36 * 64) {
            p = i >> 6; ch = i & 63; row = 128 + ch; dst = &vv[i];
        } else {
            int j = i - 36 * 64;            // 0..2047
            int t = (j >> 6) & 15;          // inner token 0..15
            ch = j & 63;
            p = (1 + (t >> 2)) * 6 + 1 + (t & 3);
            if (j < 16 * 64) { row = ch;      dst = &qq[j]; }
            else             { row = 64 + ch; dst = &kk[j - 16 * 64]; }
        }
        const float4* w4 = reinterpret_cast<const float4*>(qkv_w + row * 64);
        const float4* x4 = reinterpret_cast<const float4*>(&xp[p * 64]);
        float acc = 0.f;
        #pragma unroll
        for (int c4 = 0; c4 < 16; ++c4) {
            float4 a = w4[c4];
            float4 bb = x4[c4];
            acc += a.x * bb.x + a.y * bb.y + a.z * bb.z + a.w * bb.w;
        }
        *dst = acc;
    }
    __syncthreads();

    // ---- attention + lepe + store: 128 threads, one per (head, query token) ----
    if (tid < 128) {
        const int h  = tid >> 4;     // head 0..7
        const int tq = tid & 15;     // query token 0..15
        const float scale = 0.35355339059327373f;  // 8^-0.5
        const int qy = tq >> 2, qx = tq & 3;

        float qreg[HD];
        #pragma unroll
        for (int d = 0; d < HD; ++d) qreg[d] = qq[tq * 64 + d * 8 + h] * scale;

        float sc[16];
        float m = -1e30f;
        #pragma unroll
        for (int tk = 0; tk < 16; ++tk) {
            float s = 0.f;
            #pragma unroll
            for (int d = 0; d < HD; ++d) s += qreg[d] * kk[tk * 64 + d * 8 + h];
            int ky = tk >> 2, kx = tk & 3;
            s += bias_table[((qy - ky + 3) * 7 + (qx - kx + 3)) * 8 + h];
            sc[tk] = s;
            m = fmaxf(m, s);
        }
        float den = 0.f;
        #pragma unroll
        for (int tk = 0; tk < 16; ++tk) { sc[tk] = __expf(sc[tk] - m); den += sc[tk]; }
        const float inv = 1.f / den;

        const int iry = ys0 + qy;                  // rolled coords of this token
        const int irx = xs0 + qx;
        int oy = iry + SHIFT; if (oy >= HH) oy -= HH;   // inverse roll on H

        #pragma unroll
        for (int d = 0; d < HD; ++d) {
            const int ch = d * 8 + h;
            float o = 0.f;
            #pragma unroll
            for (int tk = 0; tk < 16; ++tk) {
                int py = 1 + (tk >> 2), px = 1 + (tk & 3);
                o += sc[tk] * vv[(py * 6 + px) * 64 + ch];
            }
            o *= inv;
            // lepe: 3x3 depthwise cross-correlation on v, centered at (qy+1,qx+1)
            float lp = 0.f;
            #pragma unroll
            for (int dy = 0; dy < 3; ++dy)
                #pragma unroll
                for (int dx = 0; dx < 3; ++dx)
                    lp += vv[((qy + dy) * 6 + (qx + dx)) * 64 + ch] * lepe_w[ch * 9 + dy * 3 + dx];
            o += lp;

            const int oc = half * 64 + ((ch + SHIFT) & 63);   // inverse roll on C (mod 64)
            const int oidx = ((b * C + oc) * HH + oy) * WW + irx;
            if (ACCUM) out[oidx] += o;
            else       out[oidx] = o;
        }
    }
}

extern "C" void kernel_launch(void* const* d_in, const int* in_sizes, int n_in,
                              void* d_out, int out_size, void* d_ws, size_t ws_size,
                              hipStream_t stream) {
    const float* x          = (const float*)d_in[0];
    const float* qkv_w      = (const float*)d_in[1];
    const float* lepe_w     = (const float*)d_in[2];
    const float* bias_table = (const float*)d_in[3];
    float* out = (float*)d_out;

    dim3 grid(48 * 48, 2, 8);
    dim3 block(256);
    // shift 0 writes every output element exactly once; shift 2 accumulates.
    swin_fused<0, false><<<grid, block, 0, stream>>>(x, qkv_w, lepe_w, bias_table, out);
    swin_fused<2, true ><<<grid, block, 0, stream>>>(x, qkv_w, lepe_w, bias_table, out);
}

// Round 2
// 2108.149 us; speedup vs baseline: 4.2684x; 4.2684x over previous
//
#include <hip/hip_runtime.h>

#define SP 4
#define XPAD 68   // xp row stride in floats: [36 pos][64 ch] at xp[p*XPAD+ch]; 68%32=4 spreads staging writes; keeps float4 alignment

// One block per (window, half, batch). SHIFT is the roll amount on (C,H).
template<int SHIFT, bool ACCUM>
__global__ __launch_bounds__(256) void swin_fused(
    const float* __restrict__ x,          // (8,128,192,192)
    const float* __restrict__ qkv_w,      // (192,64) rows: [0:64)=q, [64:128)=k, [128:192)=v
    const float* __restrict__ lepe_w,     // (64,1,3,3)
    const float* __restrict__ bias_table, // (49,8)
    float* __restrict__ out)              // (8,128,192,192)
{
    const int C = 128, HH = 192, WW = 192;
    const int win  = blockIdx.x;
    const int wy   = win / 48, wx = win % 48;
    const int half = blockIdx.y;
    const int b    = blockIdx.z;
    const int tid  = threadIdx.x;

    __shared__ float xp[36 * XPAD];   // x patch, [pos][ch]
    __shared__ float vv[64 * 37];     // v, [ch][pos] padded
    __shared__ float qq[64 * 17];     // q, [ch][tok] padded
    __shared__ float kk[64 * 17];     // k, [ch][tok] padded
    __shared__ float bias_s[392];     // 49*8
    __shared__ float lepe_s[576];     // 64*9

    const int ys0 = wy * SP, xs0 = wx * SP;

    // ---- stage small tables ----
    for (int i = tid; i < 392; i += 256) bias_s[i] = bias_table[i];
    for (int i = tid; i < 576; i += 256) lepe_s[i] = lepe_w[i];

    // ---- stage x patch: lane sweeps positions within a channel (global reads are
    //      6-float row segments; LDS writes land in ~4 distinct-bank groups) ----
    for (int i = tid; i < 64 * 36; i += 256) {
        int ch = i / 36;
        int p  = i - ch * 36;
        int py = p / 6, px = p - py * 6;
        int ry = ys0 - 1 + py;
        int rx = xs0 - 1 + px;
        float val = 0.f;
        if (ry >= 0 && ry < HH && rx >= 0 && rx < WW) {
            int oy = ry + SHIFT; if (oy >= HH) oy -= HH;
            int oc = half * 64 + ch + SHIFT; if (oc >= C) oc -= C;   // forward roll: mod 128
            val = x[((b * C + oc) * HH + oy) * WW + rx];
        }
        xp[p * XPAD + ch] = val;
    }
    __syncthreads();

    // ---- B1: v projection. thread = (ch, grp); weight row in registers;
    //      xp reads are wave-uniform (LDS broadcast) ----
    {
        const int ch  = tid & 63;
        const int grp = tid >> 6;          // 4 groups x 9 positions
        float4 w[16];
        const float4* wrow = reinterpret_cast<const float4*>(qkv_w + (128 + ch) * 64);
        #pragma unroll
        for (int c4 = 0; c4 < 16; ++c4) w[c4] = wrow[c4];
        float acc[9] = {0,0,0,0,0,0,0,0,0};
        #pragma unroll
        for (int c4 = 0; c4 < 16; ++c4) {
            const float4 wc = w[c4];
            #pragma unroll
            for (int pp = 0; pp < 9; ++pp) {
                const float4 xv = *reinterpret_cast<const float4*>(&xp[(grp * 9 + pp) * XPAD + c4 * 4]);
                acc[pp] += wc.x * xv.x + wc.y * xv.y + wc.z * xv.z + wc.w * xv.w;
            }
        }
        #pragma unroll
        for (int pp = 0; pp < 9; ++pp) vv[ch * 37 + grp * 9 + pp] = acc[pp];
    }

    // ---- B2: q,k projection for the 16 inner tokens. threads 0..127 = q, 128..255 = k ----
    {
        const int ch    = tid & 63;
        const int which = tid >> 7;        // 0 = q, 1 = k
        const int grp2  = (tid >> 6) & 1;  // 2 groups x 8 tokens
        float* dst = which ? kk : qq;
        float4 w[16];
        const float4* wrow = reinterpret_cast<const float4*>(qkv_w + (which * 64 + ch) * 64);
        #pragma unroll
        for (int c4 = 0; c4 < 16; ++c4) w[c4] = wrow[c4];
        float acc[8] = {0,0,0,0,0,0,0,0};
        #pragma unroll
        for (int c4 = 0; c4 < 16; ++c4) {
            const float4 wc = w[c4];
            #pragma unroll
            for (int t = 0; t < 8; ++t) {
                const int tok = grp2 * 8 + t;
                const int pos = (1 + (tok >> 2)) * 6 + 1 + (tok & 3);
                const float4 xv = *reinterpret_cast<const float4*>(&xp[pos * XPAD + c4 * 4]);
                acc[t] += wc.x * xv.x + wc.y * xv.y + wc.z * xv.z + wc.w * xv.w;
            }
        }
        #pragma unroll
        for (int t = 0; t < 8; ++t) dst[ch * 17 + grp2 * 8 + t] = acc[t];
    }
    __syncthreads();

    // ---- attention + lepe + store: 256 threads = (dh, h, tq); each owns 4 channels ----
    {
        const int tq = tid & 15;
        const int h  = (tid >> 4) & 7;
        const int dh = tid >> 7;           // splits the 8 dims into 2x4 channels
        const int qy = tq >> 2, qx = tq & 3;
        const float scale = 0.35355339059327373f;

        float qreg[8];
        #pragma unroll
        for (int d = 0; d < 8; ++d) qreg[d] = qq[(d * 8 + h) * 17 + tq] * scale;

        float sc[16];
        float m = -1e30f;
        #pragma unroll
        for (int tk = 0; tk < 16; ++tk) {
            float s = 0.f;
            #pragma unroll
            for (int d = 0; d < 8; ++d) s += qreg[d] * kk[(d * 8 + h) * 17 + tk];
            const int ky = tk >> 2, kx = tk & 3;
            s += bias_s[((qy - ky + 3) * 7 + (qx - kx + 3)) * 8 + h];
            sc[tk] = s;
            m = fmaxf(m, s);
        }
        float den = 0.f;
        #pragma unroll
        for (int tk = 0; tk < 16; ++tk) { sc[tk] = __expf(sc[tk] - m); den += sc[tk]; }
        const float inv = 1.f / den;

        // lepe weights for my 4 channels into registers
        float lw[4][9];
        #pragma unroll
        for (int dd = 0; dd < 4; ++dd) {
            const int ch = (dh * 4 + dd) * 8 + h;
            #pragma unroll
            for (int j = 0; j < 9; ++j) lw[dd][j] = lepe_s[ch * 9 + j];
        }

        float o[4] = {0.f, 0.f, 0.f, 0.f};
        #pragma unroll
        for (int tk = 0; tk < 16; ++tk) {
            const int p = (1 + (tk >> 2)) * 6 + 1 + (tk & 3);
            const float s = sc[tk];
            #pragma unroll
            for (int dd = 0; dd < 4; ++dd)
                o[dd] += s * vv[((dh * 4 + dd) * 8 + h) * 37 + p];
        }

        const int iry = ys0 + qy;
        const int irx = xs0 + qx;
        int oy = iry + SHIFT; if (oy >= HH) oy -= HH;   // inverse roll on H

        #pragma unroll
        for (int dd = 0; dd < 4; ++dd) {
            const int ch = (dh * 4 + dd) * 8 + h;
            float val = o[dd] * inv;
            #pragma unroll
            for (int dy = 0; dy < 3; ++dy)
                #pragma unroll
                for (int dx = 0; dx < 3; ++dx)
                    val += vv[ch * 37 + (qy + dy) * 6 + (qx + dx)] * lw[dd][dy * 3 + dx];

            const int oc = half * 64 + ((ch + SHIFT) & 63);   // inverse roll on C: mod 64 (per half)
            const int oidx = ((b * C + oc) * HH + oy) * WW + irx;
            if (ACCUM) out[oidx] += val;
            else       out[oidx] = val;
        }
    }
}

extern "C" void kernel_launch(void* const* d_in, const int* in_sizes, int n_in,
                              void* d_out, int out_size, void* d_ws, size_t ws_size,
                              hipStream_t stream) {
    const float* x          = (const float*)d_in[0];
    const float* qkv_w      = (const float*)d_in[1];
    const float* lepe_w     = (const float*)d_in[2];
    const float* bias_table = (const float*)d_in[3];
    float* out = (float*)d_out;

    dim3 grid(48 * 48, 2, 8);
    dim3 block(256);
    swin_fused<0, false><<<grid, block, 0, stream>>>(x, qkv_w, lepe_w, bias_table, out);
    swin_fused<2, true ><<<grid, block, 0, stream>>>(x, qkv_w, lepe_w, bias_table, out);
}

// Round 3
// 1040.860 us; speedup vs baseline: 8.6453x; 2.0254x over previous
//
#include <hip/hip_runtime.h>

#define SP 4

typedef __attribute__((ext_vector_type(8))) short short8v;  // 8 bf16 (4 VGPRs)
typedef __attribute__((ext_vector_type(4))) float f32x4;

__device__ inline short f2bf(float f) {
    unsigned u = __builtin_bit_cast(unsigned, f);
    unsigned r = (u + 0x7FFFu + ((u >> 16) & 1u)) >> 16;   // RNE
    return (short)r;
}

// One block per (window, half, batch). SHIFT = roll amount on (C,H).
// Projections via mfma_f32_16x16x32_bf16:
//   A (tokens x in_ch) staged in LDS in fragment order: lane l holds A[l&15][8*(l>>4)+j]
//   B (in_ch x out_ch) from global: lane l holds qkv_w[n0+(l&15)][8*(l>>4)+j]
//   D: lane l holds D[4*(l>>4)+r][l&15]
template<int SHIFT, bool ACCUM>
__global__ __launch_bounds__(256) void swin_fused(
    const float* __restrict__ x,          // (8,128,192,192)
    const float* __restrict__ qkv_w,      // (192,64)
    const float* __restrict__ lepe_w,     // (64,1,3,3)
    const float* __restrict__ bias_table, // (49,8)
    float* __restrict__ out)              // (8,128,192,192)
{
    const int C = 128, HH = 192, WW = 192;
    const int win  = blockIdx.x;
    const int wy   = win / 48, wx = win % 48;
    const int half = blockIdx.y;
    const int b    = blockIdx.z;
    const int tid  = threadIdx.x;

    // A-fragment slots: 0..5 = v-part (48 padded tokens, mt = slot>>1, kstep = slot&1)
    //                   6..7 = q/k-part (16 inner tokens, kstep = slot&1)
    __shared__ short xpA[8 * 64 * 8];   // 8 KB
    __shared__ float vs[64 * 37];       // v, [ch][pos 0..35] padded
    __shared__ float qs[64 * 17];       // q, [ch][tok] padded
    __shared__ float ks[64 * 17];       // k, [ch][tok] padded
    __shared__ float bias_s[392];
    __shared__ float lepe_s[576];

    const int ys0 = wy * SP, xs0 = wx * SP;

    for (int i = tid; i < 392; i += 256) bias_s[i] = bias_table[i];
    for (int i = tid; i < 576; i += 256) lepe_s[i] = lepe_w[i];

    // ---- stage x patch as bf16 in A-fragment order ----
    for (int item = tid; item < 512; item += 256) {
        const int slot = item >> 6;
        const int l    = item & 63;
        const int kst  = slot & 1;
        int p = 0; bool tvalid = true;
        if (slot < 6) {
            const int t48 = (slot >> 1) * 16 + (l & 15);
            tvalid = (t48 < 36);
            p = t48;
        } else {
            const int ti = l & 15;
            p = (1 + (ti >> 2)) * 6 + 1 + (ti & 3);
        }
        const int c0 = kst * 32 + (l >> 4) * 8;
        short8v pk;
        bool inb = false; int ry = 0, rx = 0;
        if (tvalid) {
            const int py = p / 6, px = p - py * 6;
            ry = ys0 - 1 + py; rx = xs0 - 1 + px;
            inb = (ry >= 0 && ry < HH && rx >= 0 && rx < WW);
        }
        if (inb) {
            int oy = ry + SHIFT; if (oy >= HH) oy -= HH;
            #pragma unroll
            for (int j = 0; j < 8; ++j) {
                int oc = half * 64 + c0 + j + SHIFT; if (oc >= C) oc -= C;
                pk[j] = f2bf(x[((b * C + oc) * HH + oy) * WW + rx]);
            }
        } else {
            #pragma unroll
            for (int j = 0; j < 8; ++j) pk[j] = 0;
        }
        *reinterpret_cast<short8v*>(&xpA[item * 8]) = pk;
    }

    // ---- B fragments (weights) from global, L1/L2-hot ----
    const int w = tid >> 6;          // wave id: owns out-channels w*16..w*16+15 of each of q,k,v
    const int l = tid & 63;
    const int nn = l & 15, g = l >> 4;
    short8v Bq[2], Bk[2], Bv[2];
    #pragma unroll
    for (int kst = 0; kst < 2; ++kst) {
        const int coff = kst * 32 + g * 8;
        {
            const float* src = qkv_w + (0 * 64 + w * 16 + nn) * 64 + coff;
            short8v pk;
            #pragma unroll
            for (int j = 0; j < 8; ++j) pk[j] = f2bf(src[j]);
            Bq[kst] = pk;
        }
        {
            const float* src = qkv_w + (1 * 64 + w * 16 + nn) * 64 + coff;
            short8v pk;
            #pragma unroll
            for (int j = 0; j < 8; ++j) pk[j] = f2bf(src[j]);
            Bk[kst] = pk;
        }
        {
            const float* src = qkv_w + (2 * 64 + w * 16 + nn) * 64 + coff;
            short8v pk;
            #pragma unroll
            for (int j = 0; j < 8; ++j) pk[j] = f2bf(src[j]);
            Bv[kst] = pk;
        }
    }
    __syncthreads();

    // ---- A fragments from LDS (lane-linear b128) + MFMA ----
    {
        short8v Aq[2], Av[3][2];
        #pragma unroll
        for (int kst = 0; kst < 2; ++kst)
            Aq[kst] = *reinterpret_cast<const short8v*>(&xpA[((6 + kst) * 64 + l) * 8]);
        #pragma unroll
        for (int mt = 0; mt < 3; ++mt)
            #pragma unroll
            for (int kst = 0; kst < 2; ++kst)
                Av[mt][kst] = *reinterpret_cast<const short8v*>(&xpA[((mt * 2 + kst) * 64 + l) * 8]);

        f32x4 accQ = {0.f, 0.f, 0.f, 0.f};
        f32x4 accK = {0.f, 0.f, 0.f, 0.f};
        f32x4 accV[3];
        #pragma unroll
        for (int mt = 0; mt < 3; ++mt) accV[mt] = (f32x4){0.f, 0.f, 0.f, 0.f};

        #pragma unroll
        for (int kst = 0; kst < 2; ++kst) {
            accQ = __builtin_amdgcn_mfma_f32_16x16x32_bf16(Aq[kst], Bq[kst], accQ, 0, 0, 0);
            accK = __builtin_amdgcn_mfma_f32_16x16x32_bf16(Aq[kst], Bk[kst], accK, 0, 0, 0);
            #pragma unroll
            for (int mt = 0; mt < 3; ++mt)
                accV[mt] = __builtin_amdgcn_mfma_f32_16x16x32_bf16(Av[mt][kst], Bv[kst], accV[mt], 0, 0, 0);
        }

        // ---- scatter D to [ch][tok] LDS ----
        const int ch = w * 16 + nn;
        #pragma unroll
        for (int r = 0; r < 4; ++r) {
            const int ti = g * 4 + r;
            qs[ch * 17 + ti] = accQ[r];
            ks[ch * 17 + ti] = accK[r];
        }
        #pragma unroll
        for (int mt = 0; mt < 3; ++mt)
            #pragma unroll
            for (int r = 0; r < 4; ++r) {
                const int tok = mt * 16 + g * 4 + r;
                if (tok < 36) vs[ch * 37 + tok] = accV[mt][r];
            }
    }
    __syncthreads();

    // ---- attention + lepe + store: 256 threads = (dh, h, tq); each owns 4 channels ----
    {
        const int tq = tid & 15;
        const int h  = (tid >> 4) & 7;
        const int dh = tid >> 7;
        const int qy = tq >> 2, qx = tq & 3;
        const float scale = 0.35355339059327373f;

        float qreg[8];
        #pragma unroll
        for (int d = 0; d < 8; ++d) qreg[d] = qs[(d * 8 + h) * 17 + tq] * scale;

        float sc[16];
        float m = -1e30f;
        #pragma unroll
        for (int tk = 0; tk < 16; ++tk) {
            float s = 0.f;
            #pragma unroll
            for (int d = 0; d < 8; ++d) s += qreg[d] * ks[(d * 8 + h) * 17 + tk];
            const int ky = tk >> 2, kx = tk & 3;
            s += bias_s[((qy - ky + 3) * 7 + (qx - kx + 3)) * 8 + h];
            sc[tk] = s;
            m = fmaxf(m, s);
        }
        float den = 0.f;
        #pragma unroll
        for (int tk = 0; tk < 16; ++tk) { sc[tk] = __expf(sc[tk] - m); den += sc[tk]; }
        const float inv = 1.f / den;

        float lw[4][9];
        #pragma unroll
        for (int dd = 0; dd < 4; ++dd) {
            const int ch = (dh * 4 + dd) * 8 + h;
            #pragma unroll
            for (int j = 0; j < 9; ++j) lw[dd][j] = lepe_s[ch * 9 + j];
        }

        float o[4] = {0.f, 0.f, 0.f, 0.f};
        #pragma unroll
        for (int tk = 0; tk < 16; ++tk) {
            const int p = (1 + (tk >> 2)) * 6 + 1 + (tk & 3);
            const float s = sc[tk];
            #pragma unroll
            for (int dd = 0; dd < 4; ++dd)
                o[dd] += s * vs[((dh * 4 + dd) * 8 + h) * 37 + p];
        }

        const int iry = ys0 + qy;
        const int irx = xs0 + qx;
        int oy = iry + SHIFT; if (oy >= HH) oy -= HH;   // inverse roll on H

        #pragma unroll
        for (int dd = 0; dd < 4; ++dd) {
            const int ch = (dh * 4 + dd) * 8 + h;
            float val = o[dd] * inv;
            #pragma unroll
            for (int dy = 0; dy < 3; ++dy)
                #pragma unroll
                for (int dx = 0; dx < 3; ++dx)
                    val += vs[ch * 37 + (qy + dy) * 6 + (qx + dx)] * lw[dd][dy * 3 + dx];

            const int oc = half * 64 + ((ch + SHIFT) & 63);   // inverse roll on C (per-half, mod 64)
            const int oidx = ((b * C + oc) * HH + oy) * WW + irx;
            if (ACCUM) out[oidx] += val;
            else       out[oidx] = val;
        }
    }
}

extern "C" void kernel_launch(void* const* d_in, const int* in_sizes, int n_in,
                              void* d_out, int out_size, void* d_ws, size_t ws_size,
                              hipStream_t stream) {
    const float* x          = (const float*)d_in[0];
    const float* qkv_w      = (const float*)d_in[1];
    const float* lepe_w     = (const float*)d_in[2];
    const float* bias_table = (const float*)d_in[3];
    float* out = (float*)d_out;

    dim3 grid(48 * 48, 2, 8);
    dim3 block(256);
    swin_fused<0, false><<<grid, block, 0, stream>>>(x, qkv_w, lepe_w, bias_table, out);
    swin_fused<2, true ><<<grid, block, 0, stream>>>(x, qkv_w, lepe_w, bias_table, out);
}

// Round 5
// 453.725 us; speedup vs baseline: 19.8325x; 2.2940x over previous
//
#include <hip/hip_runtime.h>

typedef __attribute__((ext_vector_type(8))) short short8v;  // 8 bf16
typedef __attribute__((ext_vector_type(4))) float f32x4;

__device__ inline unsigned short f2bf(float f) {
    unsigned u = __builtin_bit_cast(unsigned, f);
    return (unsigned short)((u + 0x7FFFu + ((u >> 16) & 1u)) >> 16);   // RNE
}
__device__ inline float bf2f(unsigned short u) {
    return __builtin_bit_cast(float, ((unsigned)u) << 16);
}

// ---------------- prep 1: qkv_w -> bf16 B-fragments in ws ----------------
// frag = which*8 + nt*2 + kst ; lane l holds w[which*64+nt*16+(l&15)][kst*32+(l>>4)*8+j]
__global__ __launch_bounds__(256) void prep_weights(const float* __restrict__ qkv_w,
                                                    unsigned short* __restrict__ wf) {
    int it = blockIdx.x * 256 + threadIdx.x;      // 1536 items
    if (it >= 1536) return;
    int l = it & 63, frag = it >> 6;
    int which = frag >> 3, nt = (frag >> 1) & 3, kst = frag & 1;
    const float* src = qkv_w + (which * 64 + nt * 16 + (l & 15)) * 64 + kst * 32 + (l >> 4) * 8;
    short8v pk;
    #pragma unroll
    for (int j = 0; j < 8; ++j) pk[j] = (short)f2bf(src[j]);
    *reinterpret_cast<short8v*>(wf + it * 8) = pk;
}

// ---------------- prep 2: x (b,c,y,x) fp32 -> xbf_s (b,y,x,c) bf16, pre-rolled ----------------
// xbf_s[b][y'][x][c'] = x[b][(c'+s)%128][(y'+s)%192][x]
__global__ __launch_bounds__(256) void prep_x(const float* __restrict__ x,
                                              unsigned short* __restrict__ xbf0,
                                              unsigned short* __restrict__ xbf2) {
    const int xt = blockIdx.x;   // 0..5 (32-wide tiles)
    const int y  = blockIdx.y;   // source row
    const int b  = blockIdx.z;
    const int x0 = xt * 32;
    __shared__ float buf[128 * 33];

    for (int it = threadIdx.x; it < 1024; it += 256) {
        int c = it >> 3, xq = it & 7;
        const float4 v = *reinterpret_cast<const float4*>(
            x + ((b * 128 + c) * 192 + y) * 192 + x0 + xq * 4);
        float* d = &buf[c * 33 + xq * 4];
        d[0] = v.x; d[1] = v.y; d[2] = v.z; d[3] = v.w;
    }
    __syncthreads();

    #pragma unroll
    for (int si = 0; si < 2; ++si) {
        const int s = si * 2;
        unsigned short* dst = si ? xbf2 : xbf0;
        int ydst = y - s; if (ydst < 0) ydst += 192;
        for (int it = threadIdx.x; it < 512; it += 256) {
            int xl = it >> 4, c8 = it & 15;
            short8v pk;
            #pragma unroll
            for (int j = 0; j < 8; ++j) {
                int c = (s + c8 * 8 + j) & 127;
                pk[j] = (short)f2bf(buf[c * 33 + xl]);
            }
            *reinterpret_cast<short8v*>(dst + ((b * 192 + ydst) * 192 + x0 + xl) * 128 + c8 * 8) = pk;
        }
    }
}

// ---------------- main: 4-window strip per block ----------------
template<int SHIFT, bool ACCUM>
__global__ __launch_bounds__(256) void swin_main(
    const unsigned short* __restrict__ xbf,   // pre-rolled (b,y,x,128) bf16
    const unsigned short* __restrict__ wfrag,
    const float* __restrict__ lepe_w,
    const float* __restrict__ bias_table,
    float* __restrict__ out)
{
    const int bx = blockIdx.x;                 // wy*12 + strip
    const int wy = bx / 12, strip = bx % 12;
    const int half = blockIdx.y, b = blockIdx.z;
    const int tid = threadIdx.x;
    const int w = tid >> 6, l = tid & 63;      // wave = window within strip

    __shared__ unsigned short xv[108 * 64];    // x patch, later reused as v   [pos][64ch] swizzled
    __shared__ unsigned short qs[64 * 64];     // q [tok][64 ch' head-major] swizzled
    __shared__ unsigned short ks[64 * 64];
    __shared__ float bias_s[392];
    __shared__ float lepe_s[576];              // permuted: [ch'=h*8+d][9]

    for (int i = tid; i < 392; i += 256) bias_s[i] = bias_table[i];
    for (int i = tid; i < 576; i += 256) {
        int ch = i / 9, j = i - ch * 9;
        int chp = (ch & 7) * 8 + (ch >> 3);
        lepe_s[chp * 9 + j] = lepe_w[i];
    }

    // ---- stage tile: linear LDS dest, source chunk XOR-pre-swizzled (rule #21) ----
    const int ry0 = wy * 4 - 1, rx0 = strip * 16 - 1;
    for (int it = tid; it < 864; it += 256) {
        const int pos = it >> 3, slot = it & 7;
        const int py = pos / 18, px = pos - py * 18;
        const int ry = ry0 + py, rx = rx0 + px;
        short8v val = {0, 0, 0, 0, 0, 0, 0, 0};
        if (ry >= 0 && ry < 192 && rx >= 0 && rx < 192) {
            const int srcslot = slot ^ (pos & 7);
            val = *reinterpret_cast<const short8v*>(
                xbf + ((b * 192 + ry) * 192 + rx) * 128 + half * 64 + srcslot * 8);
        }
        *reinterpret_cast<short8v*>(&xv[pos * 64 + slot * 8]) = val;
    }
    __syncthreads();

    // ---- A fragments (swizzled reads) ----
    const int tok16 = l & 15, g = l >> 4;
    short8v Aq[2], Av[3][2];
    {
        const int posq = (1 + (tok16 >> 2)) * 18 + w * 4 + 1 + (tok16 & 3);
        #pragma unroll
        for (int kst = 0; kst < 2; ++kst) {
            int chunk = (kst * 4 + g) ^ (posq & 7);
            Aq[kst] = *reinterpret_cast<const short8v*>(&xv[posq * 64 + chunk * 8]);
        }
        #pragma unroll
        for (int mt = 0; mt < 3; ++mt) {
            int t = mt * 16 + tok16;
            int posv = (t < 36) ? ((t / 6) * 18 + w * 4 + (t % 6)) : 0;
            #pragma unroll
            for (int kst = 0; kst < 2; ++kst) {
                int chunk = (kst * 4 + g) ^ (posv & 7);
                Av[mt][kst] = *reinterpret_cast<const short8v*>(&xv[posv * 64 + chunk * 8]);
            }
        }
    }
    __syncthreads();   // all A reads done before v overwrites xv

    // ---- MFMA + scatter (per out-ch tile nt); channels stored head-major ch'=(ch&7)*8+(ch>>3) ----
    #pragma unroll
    for (int nt = 0; nt < 4; ++nt) {
        short8v Bq[2], Bk[2], Bv[2];
        #pragma unroll
        for (int kst = 0; kst < 2; ++kst) {
            Bq[kst] = *reinterpret_cast<const short8v*>(wfrag + (((0 * 8 + nt * 2 + kst) * 64 + l) * 8));
            Bk[kst] = *reinterpret_cast<const short8v*>(wfrag + (((1 * 8 + nt * 2 + kst) * 64 + l) * 8));
            Bv[kst] = *reinterpret_cast<const short8v*>(wfrag + (((2 * 8 + nt * 2 + kst) * 64 + l) * 8));
        }
        f32x4 aQ = {0.f,0.f,0.f,0.f}, aK = {0.f,0.f,0.f,0.f};
        f32x4 aV[3];
        #pragma unroll
        for (int mt = 0; mt < 3; ++mt) aV[mt] = (f32x4){0.f,0.f,0.f,0.f};
        #pragma unroll
        for (int kst = 0; kst < 2; ++kst) {
            aQ = __builtin_amdgcn_mfma_f32_16x16x32_bf16(Aq[kst], Bq[kst], aQ, 0, 0, 0);
            aK = __builtin_amdgcn_mfma_f32_16x16x32_bf16(Aq[kst], Bk[kst], aK, 0, 0, 0);
            #pragma unroll
            for (int mt = 0; mt < 3; ++mt)
                aV[mt] = __builtin_amdgcn_mfma_f32_16x16x32_bf16(Av[mt][kst], Bv[kst], aV[mt], 0, 0, 0);
        }
        const int ch  = nt * 16 + tok16;
        const int chp = (ch & 7) * 8 + (ch >> 3);
        #pragma unroll
        for (int r = 0; r < 4; ++r) {
            const int qtok = w * 16 + 4 * g + r;
            const int pb = (((chp >> 3) ^ (qtok & 7)) * 8 + (chp & 7));
            qs[qtok * 64 + pb] = f2bf(aQ[r]);
            ks[qtok * 64 + pb] = f2bf(aK[r]);
        }
        #pragma unroll
        for (int mt = 0; mt < 3; ++mt)
            #pragma unroll
            for (int r = 0; r < 4; ++r) {
                int t = mt * 16 + 4 * g + r;
                if (t < 36) {
                    int pos = (t / 6) * 18 + w * 4 + (t % 6);
                    int pb = (((chp >> 3) ^ (pos & 7)) * 8 + (chp & 7));
                    xv[pos * 64 + pb] = f2bf(aV[mt][r]);   // waves overlap: identical values, benign
                }
            }
    }
    __syncthreads();

    // ---- attention + lepe + store: wave = window, lane = (h, tq&7), 2 query tokens per lane ----
    {
        const int h = l >> 3, tqp = l & 7;
        const int qy0 = tqp >> 2, qx0 = tqp & 3;   // tq0 = tqp ; tq1 = tqp+8 -> qy0+2, qx0
        const float scale = 0.35355339059327373f;

        float q0[8], q1[8];
        {
            int t0 = w * 16 + tqp, t1 = t0 + 8;
            short8v r0 = *reinterpret_cast<const short8v*>(&qs[t0 * 64 + (h ^ (t0 & 7)) * 8]);
            short8v r1 = *reinterpret_cast<const short8v*>(&qs[t1 * 64 + (h ^ (t1 & 7)) * 8]);
            #pragma unroll
            for (int d = 0; d < 8; ++d) {
                q0[d] = bf2f((unsigned short)r0[d]) * scale;
                q1[d] = bf2f((unsigned short)r1[d]) * scale;
            }
        }
        float sc0[16], sc1[16], m0 = -1e30f, m1 = -1e30f;
        #pragma unroll
        for (int tk = 0; tk < 16; ++tk) {
            int kt = w * 16 + tk;
            short8v kr = *reinterpret_cast<const short8v*>(&ks[kt * 64 + (h ^ (kt & 7)) * 8]);
            float s0 = 0.f, s1 = 0.f;
            #pragma unroll
            for (int d = 0; d < 8; ++d) {
                float kv = bf2f((unsigned short)kr[d]);
                s0 += q0[d] * kv; s1 += q1[d] * kv;
            }
            const int ky = tk >> 2, kx = tk & 3;
            s0 += bias_s[((qy0 - ky + 3) * 7 + (qx0 - kx + 3)) * 8 + h];
            s1 += bias_s[((qy0 + 2 - ky + 3) * 7 + (qx0 - kx + 3)) * 8 + h];
            sc0[tk] = s0; sc1[tk] = s1;
            m0 = fmaxf(m0, s0); m1 = fmaxf(m1, s1);
        }
        float den0 = 0.f, den1 = 0.f;
        #pragma unroll
        for (int tk = 0; tk < 16; ++tk) {
            sc0[tk] = __expf(sc0[tk] - m0); den0 += sc0[tk];
            sc1[tk] = __expf(sc1[tk] - m1); den1 += sc1[tk];
        }
        const float inv0 = 1.f / den0, inv1 = 1.f / den1;

        float o0[8] = {0,0,0,0,0,0,0,0}, o1[8] = {0,0,0,0,0,0,0,0};
        #pragma unroll
        for (int tk = 0; tk < 16; ++tk) {
            int pos = (1 + (tk >> 2)) * 18 + w * 4 + 1 + (tk & 3);
            short8v vr = *reinterpret_cast<const short8v*>(&xv[pos * 64 + (h ^ (pos & 7)) * 8]);
            #pragma unroll
            for (int d = 0; d < 8; ++d) {
                float vv = bf2f((unsigned short)vr[d]);
                o0[d] += sc0[tk] * vv; o1[d] += sc1[tk] * vv;
            }
        }
        #pragma unroll
        for (int d = 0; d < 8; ++d) { o0[d] *= inv0; o1[d] *= inv1; }

        // lepe (3x3 depthwise on v) for both query tokens
        #pragma unroll
        for (int dy = 0; dy < 3; ++dy)
            #pragma unroll
            for (int dx = 0; dx < 3; ++dx) {
                int p0 = (qy0 + dy) * 18 + w * 4 + qx0 + dx;
                int p1 = p0 + 36;  // qy0+2 rows below
                short8v v0 = *reinterpret_cast<const short8v*>(&xv[p0 * 64 + (h ^ (p0 & 7)) * 8]);
                short8v v1 = *reinterpret_cast<const short8v*>(&xv[p1 * 64 + (h ^ (p1 & 7)) * 8]);
                #pragma unroll
                for (int d = 0; d < 8; ++d) {
                    float lw = lepe_s[(h * 8 + d) * 9 + dy * 3 + dx];
                    o0[d] += bf2f((unsigned short)v0[d]) * lw;
                    o1[d] += bf2f((unsigned short)v1[d]) * lw;
                }
            }

        const int ox = strip * 16 + w * 4 + qx0;
        int oy0 = wy * 4 + qy0 + SHIFT;     if (oy0 >= 192) oy0 -= 192;
        int oy1 = wy * 4 + qy0 + 2 + SHIFT; if (oy1 >= 192) oy1 -= 192;
        #pragma unroll
        for (int d = 0; d < 8; ++d) {
            const int oc = half * 64 + ((d * 8 + h + SHIFT) & 63);
            const int i0 = ((b * 128 + oc) * 192 + oy0) * 192 + ox;
            const int i1 = ((b * 128 + oc) * 192 + oy1) * 192 + ox;
            if (ACCUM) { out[i0] += o0[d]; out[i1] += o1[d]; }
            else       { out[i0]  = o0[d]; out[i1]  = o1[d]; }
        }
    }
}

// ---------------- fallback (round-3 kernel, used only if ws too small) ----------------
template<int SHIFT, bool ACCUM>
__global__ __launch_bounds__(256) void swin_fb(
    const float* __restrict__ x, const float* __restrict__ qkv_w,
    const float* __restrict__ lepe_w, const float* __restrict__ bias_table,
    float* __restrict__ out)
{
    const int C = 128, HH = 192, WW = 192;
    const int win = blockIdx.x, wy = win / 48, wx = win % 48;
    const int half = blockIdx.y, b = blockIdx.z, tid = threadIdx.x;
    __shared__ short xpA[8 * 64 * 8];
    __shared__ float vs[64 * 37], qsf[64 * 17], ksf[64 * 17];
    __shared__ float bias_s[392], lepe_s[576];
    const int ys0 = wy * 4, xs0 = wx * 4;
    for (int i = tid; i < 392; i += 256) bias_s[i] = bias_table[i];
    for (int i = tid; i < 576; i += 256) lepe_s[i] = lepe_w[i];
    for (int item = tid; item < 512; item += 256) {
        const int slot = item >> 6, l = item & 63, kst = slot & 1;
        int p = 0; bool tvalid = true;
        if (slot < 6) { int t48 = (slot >> 1) * 16 + (l & 15); tvalid = (t48 < 36); p = t48; }
        else { int ti = l & 15; p = (1 + (ti >> 2)) * 6 + 1 + (ti & 3); }
        const int c0 = kst * 32 + (l >> 4) * 8;
        short8v pk;
        #pragma unroll
        for (int j = 0; j < 8; ++j) pk[j] = 0;
        if (tvalid) {
            int py = p / 6, px = p - py * 6;
            int ry = ys0 - 1 + py, rx = xs0 - 1 + px;
            if (ry >= 0 && ry < HH && rx >= 0 && rx < WW) {
                int oy = ry + SHIFT; if (oy >= HH) oy -= HH;
                #pragma unroll
                for (int j = 0; j < 8; ++j) {
                    int oc = half * 64 + c0 + j + SHIFT; if (oc >= C) oc -= C;
                    pk[j] = (short)f2bf(x[((b * C + oc) * HH + oy) * WW + rx]);
                }
            }
        }
        *reinterpret_cast<short8v*>(&xpA[item * 8]) = pk;
    }
    const int w = tid >> 6, l = tid & 63, nn = l & 15, g = l >> 4;
    short8v Bq[2], Bk[2], Bv[2];
    #pragma unroll
    for (int kst = 0; kst < 2; ++kst) {
        const int coff = kst * 32 + g * 8;
        const float* s0 = qkv_w + (w * 16 + nn) * 64 + coff;
        const float* s1 = qkv_w + (64 + w * 16 + nn) * 64 + coff;
        const float* s2 = qkv_w + (128 + w * 16 + nn) * 64 + coff;
        short8v p0, p1, p2;
        #pragma unroll
        for (int j = 0; j < 8; ++j) { p0[j] = (short)f2bf(s0[j]); p1[j] = (short)f2bf(s1[j]); p2[j] = (short)f2bf(s2[j]); }
        Bq[kst] = p0; Bk[kst] = p1; Bv[kst] = p2;
    }
    __syncthreads();
    {
        short8v Aq[2], Avf[3][2];
        #pragma unroll
        for (int kst = 0; kst < 2; ++kst)
            Aq[kst] = *reinterpret_cast<const short8v*>(&xpA[((6 + kst) * 64 + l) * 8]);
        #pragma unroll
        for (int mt = 0; mt < 3; ++mt)
            #pragma unroll
            for (int kst = 0; kst < 2; ++kst)
                Avf[mt][kst] = *reinterpret_cast<const short8v*>(&xpA[((mt * 2 + kst) * 64 + l) * 8]);
        f32x4 aQ = {0,0,0,0}, aK = {0,0,0,0}; f32x4 aV[3];
        #pragma unroll
        for (int mt = 0; mt < 3; ++mt) aV[mt] = (f32x4){0,0,0,0};
        #pragma unroll
        for (int kst = 0; kst < 2; ++kst) {
            aQ = __builtin_amdgcn_mfma_f32_16x16x32_bf16(Aq[kst], Bq[kst], aQ, 0, 0, 0);
            aK = __builtin_amdgcn_mfma_f32_16x16x32_bf16(Aq[kst], Bk[kst], aK, 0, 0, 0);
            #pragma unroll
            for (int mt = 0; mt < 3; ++mt)
                aV[mt] = __builtin_amdgcn_mfma_f32_16x16x32_bf16(Avf[mt][kst], Bv[kst], aV[mt], 0, 0, 0);
        }
        const int ch = w * 16 + nn;
        #pragma unroll
        for (int r = 0; r < 4; ++r) { qsf[ch * 17 + g * 4 + r] = aQ[r]; ksf[ch * 17 + g * 4 + r] = aK[r]; }
        #pragma unroll
        for (int mt = 0; mt < 3; ++mt)
            #pragma unroll
            for (int r = 0; r < 4; ++r) { int tok = mt * 16 + g * 4 + r; if (tok < 36) vs[ch * 37 + tok] = aV[mt][r]; }
    }
    __syncthreads();
    {
        const int tq = tid & 15, h = (tid >> 4) & 7, dh = tid >> 7;
        const int qy = tq >> 2, qx = tq & 3;
        const float scale = 0.35355339059327373f;
        float qreg[8];
        #pragma unroll
        for (int d = 0; d < 8; ++d) qreg[d] = qsf[(d * 8 + h) * 17 + tq] * scale;
        float sc[16]; float m = -1e30f;
        #pragma unroll
        for (int tk = 0; tk < 16; ++tk) {
            float s = 0.f;
            #pragma unroll
            for (int d = 0; d < 8; ++d) s += qreg[d] * ksf[(d * 8 + h) * 17 + tk];
            s += bias_s[((qy - (tk >> 2) + 3) * 7 + (qx - (tk & 3) + 3)) * 8 + h];
            sc[tk] = s; m = fmaxf(m, s);
        }
        float den = 0.f;
        #pragma unroll
        for (int tk = 0; tk < 16; ++tk) { sc[tk] = __expf(sc[tk] - m); den += sc[tk]; }
        const float inv = 1.f / den;
        float lw[4][9];
        #pragma unroll
        for (int dd = 0; dd < 4; ++dd) {
            int ch = (dh * 4 + dd) * 8 + h;
            #pragma unroll
            for (int j = 0; j < 9; ++j) lw[dd][j] = lepe_s[ch * 9 + j];
        }
        float o[4] = {0,0,0,0};
        #pragma unroll
        for (int tk = 0; tk < 16; ++tk) {
            int p = (1 + (tk >> 2)) * 6 + 1 + (tk & 3); float s = sc[tk];
            #pragma unroll
            for (int dd = 0; dd < 4; ++dd) o[dd] += s * vs[((dh * 4 + dd) * 8 + h) * 37 + p];
        }
        int oy = ys0 + qy + SHIFT; if (oy >= HH) oy -= HH;
        const int irx = xs0 + qx;
        #pragma unroll
        for (int dd = 0; dd < 4; ++dd) {
            const int ch = (dh * 4 + dd) * 8 + h;
            float val = o[dd] * inv;
            #pragma unroll
            for (int dy = 0; dy < 3; ++dy)
                #pragma unroll
                for (int dx = 0; dx < 3; ++dx)
                    val += vs[ch * 37 + (qy + dy) * 6 + (qx + dx)] * lw[dd][dy * 3 + dx];
            const int oc = half * 64 + ((ch + SHIFT) & 63);
            const int oidx = ((b * C + oc) * HH + oy) * WW + irx;
            if (ACCUM) out[oidx] += val; else out[oidx] = val;
        }
    }
}

extern "C" void kernel_launch(void* const* d_in, const int* in_sizes, int n_in,
                              void* d_out, int out_size, void* d_ws, size_t ws_size,
                              hipStream_t stream) {
    const float* x          = (const float*)d_in[0];
    const float* qkv_w      = (const float*)d_in[1];
    const float* lepe_w     = (const float*)d_in[2];
    const float* bias_table = (const float*)d_in[3];
    float* out = (float*)d_out;

    const size_t XBF_BYTES = 8UL * 192 * 192 * 128 * 2;        // 75,497,472
    const size_t NEED = 32768 + 2 * XBF_BYTES;

    if (ws_size >= NEED) {
        unsigned short* wf   = (unsigned short*)d_ws;
        unsigned short* xbf0 = (unsigned short*)((char*)d_ws + 32768);
        unsigned short* xbf2 = (unsigned short*)((char*)d_ws + 32768 + XBF_BYTES);
        prep_weights<<<6, 256, 0, stream>>>(qkv_w, wf);
        prep_x<<<dim3(6, 192, 8), 256, 0, stream>>>(x, xbf0, xbf2);
        dim3 grid(576, 2, 8);
        swin_main<0, false><<<grid, 256, 0, stream>>>(xbf0, wf, lepe_w, bias_table, out);
        swin_main<2, true ><<<grid, 256, 0, stream>>>(xbf2, wf, lepe_w, bias_table, out);
    } else {
        dim3 grid(48 * 48, 2, 8);
        swin_fb<0, false><<<grid, 256, 0, stream>>>(x, qkv_w, lepe_w, bias_table, out);
        swin_fb<2, true ><<<grid, 256, 0, stream>>>(x, qkv_w, lepe_w, bias_table, out);
    }
}